// Round 16
// baseline (1545.166 us; speedup 1.0000x reference)
//
#include <hip/hip_runtime.h>
#include <hip/hip_bf16.h>
#include <stdint.h>

#define B 8
#define NN 16383
#define INDIM 300
#define HDIM 512
#define EDIM 100

typedef short bf16x8 __attribute__((ext_vector_type(8)));
typedef float f32x4 __attribute__((ext_vector_type(4)));
typedef unsigned short ushort_t;

__device__ __forceinline__ float sigmoidf_(float v) { return 1.0f / (1.0f + __expf(-v)); }

__device__ __forceinline__ ushort_t f2b(float f) {
    union { float f; unsigned int u; } x; x.f = f;
    unsigned int u = x.u;
    return (ushort_t)((u + 0x7FFFu + ((u >> 16) & 1u)) >> 16);
}
__device__ __forceinline__ float b2f(ushort_t s) {
    union { float f; unsigned int u; } x; x.u = ((unsigned int)s) << 16; return x.f;
}

// packed h/c layout (K=512): elem (R, col) ->
//   (R>>4)*8192 + (col>>5)*512 + ((col>>3)&3)*128 + (R&15)*8 + (col&7)
__device__ __forceinline__ unsigned int pidx(int R, int col) {
    return (unsigned int)((R >> 4) * 8192 + (col >> 5) * 512 + ((col >> 3) & 3) * 128
                          + (R & 15) * 8 + (col & 7));
}

// x-pack level base: tile-granular. lvl 0 (start=0) -> 0; else (start+1)*2560.
__device__ __forceinline__ size_t xlvl_base(int start) {
    return start ? (size_t)(start + 1) * 2560 : (size_t)0;
}

// ---------------- pack weights into MFMA fragment order (index16 = out-col, 8 k's).
__global__ __launch_bounds__(256) void pack_kernel(
    const float* __restrict__ W, ushort_t* __restrict__ out,
    int Kdim, int Kt, int total)
{
    int idx = blockIdx.x * 256 + threadIdx.x;
    if (idx >= total) return;
    int lane = idx & 63;
    int kt = (idx >> 6) % Kt;
    int nt = idx / (Kt << 6);
    int n = nt * 16 + (lane & 15);
    int kb = kt * 32 + (lane >> 4) * 8;
    ushort_t v[8];
#pragma unroll
    for (int i = 0; i < 8; ++i) {
        int k = kb + i;
        v[i] = (k < Kdim) ? f2b(W[(size_t)n * Kdim + k]) : (ushort_t)0;
    }
    *reinterpret_cast<uint4*>(out + (size_t)idx * 8) = *reinterpret_cast<const uint4*>(v);
}

// ---------------- pack inputs x into MFMA fragment layout, level-local rows.
__global__ __launch_bounds__(256) void xpack_kernel(
    const float* __restrict__ inputs, ushort_t* __restrict__ xpk)
{
    int tid = blockIdx.x * 256 + threadIdx.x;
    if (tid >= NN * 8 * 40) return;
    int kr = tid & 3;
    int kt = (tid >> 2) % 10;
    int rb = tid / 40;           // g*8 + b
    int g = rb >> 3, b = rb & 7;
    int lvl = 31 - __clz(g + 1);
    int start = (1 << lvl) - 1;
    int R = (g - start) * 8 + b;
    int k0 = kt * 32 + kr * 8;
    ushort_t v[8];
#pragma unroll
    for (int i = 0; i < 8; i += 4) {
        int k = k0 + i;
        float4 xv = make_float4(0.f, 0.f, 0.f, 0.f);
        if (k + 4 <= INDIM)
            xv = *reinterpret_cast<const float4*>(&inputs[((size_t)b * NN + g) * INDIM + k]);
        v[i] = f2b(xv.x); v[i + 1] = f2b(xv.y); v[i + 2] = f2b(xv.z); v[i + 3] = f2b(xv.w);
    }
    size_t o = xlvl_base(start) + (size_t)(R >> 4) * 5120
             + (size_t)kt * 512 + (size_t)kr * 128 + (size_t)(R & 15) * 8;
    *reinterpret_cast<uint4*>(xpk + o) = *reinterpret_cast<const uint4*>(v);
}

// ---------------- children: 4 parents/block, pp = blockIdx.y. SWAPPED-operand MFMA:
// acc = mfma(Wfrag, datafrag) -> lane holds 4 consecutive out-cols x 1 row. No epi LDS.
__global__ __launch_bounds__(256) void children_kernel(
    const ushort_t* __restrict__ xpk, const float* __restrict__ edge_inputs,
    const ushort_t* __restrict__ pWfx, const float* __restrict__ bfx,
    const ushort_t* __restrict__ pWfh, const float* __restrict__ bfh,
    const ushort_t* __restrict__ pWe,  const float* __restrict__ be,
    const ushort_t* __restrict__ hX, const ushort_t* __restrict__ cX,
    ushort_t* __restrict__ hY, ushort_t* __restrict__ cY,
    int start, int n)
{
    const int nb = blockIdx.x * 4;
    const int pp = blockIdx.y;
    const int t = threadIdx.x;
    const int w = t >> 6, lane = t & 63;
    const int kr = lane >> 4, cl = lane & 15;

    __shared__ ushort_t wc[64][136];    // 17.4 KB (only LDS)

    // stage wc (rows kid*32 + p*8 + b)
    for (int i = t; i < 64 * 32; i += 256) {
        int r = i >> 5, ch = i & 31;
        int kid = r >> 5, pr = r & 31, p = pr >> 3, b = pr & 7;
        int e = ch * 4;
        ushort_t vv[4] = {0, 0, 0, 0};
        if (e < EDIM && (nb + p) < n) {
            float4 xv = *reinterpret_cast<const float4*>(
                &edge_inputs[((size_t)b * NN + 2 * (start + nb + p) + 1 + kid) * EDIM + e]);
            vv[0] = f2b(xv.x); vv[1] = f2b(xv.y); vv[2] = f2b(xv.z); vv[3] = f2b(xv.w);
        }
        *reinterpret_cast<uint2*>(&wc[r][e]) = *reinterpret_cast<const uint2*>(vv);
    }
    __syncthreads();

    const bf16x8* fWfx = reinterpret_cast<const bf16x8*>(pWfx);
    const bf16x8* fWfh = reinterpret_cast<const bf16x8*>(pWfh);
    const bf16x8* fWe  = reinterpret_cast<const bf16x8*>(pWe);

    // x frags (level packed layout), tiles blockIdx.x*2, +1; index16 = cl
    const ushort_t* xb = xpk + xlvl_base(start) + (size_t)(blockIdx.x * 2) * 5120 + (size_t)cl * 8;

    // h/c child frag offsets for f GEMM: frag col cl <-> (node nb+2*mh+(cl>>3), kid, b=cl&7)
    unsigned int cbase[4];
#pragma unroll
    for (int mt = 0; mt < 4; ++mt) {
        int kid = mt >> 1, mh = mt & 1;
        int p = 2 * mh + (cl >> 3);
        int b = cl & 7;
        cbase[mt] = ((nb + p) < n)
            ? (unsigned int)((nb + p) * 8192 + (kr * 16 + 8 * kid + b) * 8)
            : 0u;
    }

    const int ntb = w * 8 + pp * 4;
    const int eo = (kr & 1) * 4;   // element offset within 8-col group

    // ---- xf GEMM (K=320) swapped: xfa[q][mh][r] = xf(parent row mh*16+cl, col (ntb+q)*16+kr*4+r)
    f32x4 xfa[4][2];
#pragma unroll
    for (int q = 0; q < 4; ++q)
#pragma unroll
        for (int mh = 0; mh < 2; ++mh)
#pragma unroll
            for (int r = 0; r < 4; ++r) xfa[q][mh][r] = 0.f;
#pragma unroll 2
    for (int kt = 0; kt < 10; ++kt) {
        bf16x8 a0 = *reinterpret_cast<const bf16x8*>(xb + kt * 512 + kr * 128);
        bf16x8 a1 = *reinterpret_cast<const bf16x8*>(xb + 5120 + kt * 512 + kr * 128);
#pragma unroll
        for (int q = 0; q < 4; ++q) {
            bf16x8 bf_ = fWfx[(size_t)((ntb + q) * 10 + kt) * 64 + lane];
            xfa[q][0] = __builtin_amdgcn_mfma_f32_16x16x32_bf16(bf_, a0, xfa[q][0], 0, 0, 0);
            xfa[q][1] = __builtin_amdgcn_mfma_f32_16x16x32_bf16(bf_, a1, xfa[q][1], 0, 0, 0);
        }
    }
#pragma unroll
    for (int q = 0; q < 4; ++q) {
        float bv[4];
        *reinterpret_cast<float4*>(bv) = *reinterpret_cast<const float4*>(&bfx[(ntb + q) * 16 + kr * 4]);
#pragma unroll
        for (int mh = 0; mh < 2; ++mh)
#pragma unroll
            for (int r = 0; r < 4; ++r) xfa[q][mh][r] += bv[r];
    }

    // ---- ex GEMM (K=128) swapped + fused h_sum epilogue
    {
        f32x4 eacc[4][4];
#pragma unroll
        for (int q = 0; q < 4; ++q)
#pragma unroll
            for (int mt = 0; mt < 4; ++mt)
#pragma unroll
                for (int r = 0; r < 4; ++r) eacc[q][mt][r] = 0.f;
#pragma unroll
        for (int kt = 0; kt < 4; ++kt) {
            bf16x8 av[4];
#pragma unroll
            for (int mt = 0; mt < 4; ++mt)
                av[mt] = *reinterpret_cast<const bf16x8*>(&wc[mt * 16 + cl][kt * 32 + kr * 8]);
#pragma unroll
            for (int q = 0; q < 4; ++q) {
                bf16x8 bf_ = fWe[(size_t)((ntb + q) * 4 + kt) * 64 + lane];
#pragma unroll
                for (int mt = 0; mt < 4; ++mt)
                    eacc[q][mt] = __builtin_amdgcn_mfma_f32_16x16x32_bf16(bf_, av[mt], eacc[q][mt], 0, 0, 0);
            }
        }
#pragma unroll
        for (int q = 0; q < 4; ++q) {
            const int ct = ntb + q;
            float be4[4];
            *reinterpret_cast<float4*>(be4) = *reinterpret_cast<const float4*>(&be[ct * 16 + kr * 4]);
            const int colc = (ct >> 1) * 512 + (((ct & 1) << 1) + (kr >> 1)) * 128;
#pragma unroll
            for (int mh = 0; mh < 2; ++mh) {
                int pr = mh * 16 + cl;
                int p = pr >> 3, b = pr & 7;
                int np = nb + p;
                if (np >= n) continue;
                unsigned int hb0 = (unsigned int)(np * 8192 + colc + b * 8 + eo);
                ushort_t h0s[4], h1s[4];
                *reinterpret_cast<uint2*>(h0s) = *reinterpret_cast<const uint2*>(hX + hb0);
                *reinterpret_cast<uint2*>(h1s) = *reinterpret_cast<const uint2*>(hX + hb0 + 64);
                ushort_t res[4];
#pragma unroll
                for (int r = 0; r < 4; ++r) {
                    float e0 = sigmoidf_(eacc[q][mh][r] + be4[r]);
                    float e1 = sigmoidf_(eacc[q][mh + 2][r] + be4[r]);
                    res[r] = f2b(e0 * b2f(h0s[r]) + e1 * b2f(h1s[r]));
                }
                *reinterpret_cast<uint2*>(hY + (unsigned int)((np >> 1) * 8192 + colc
                        + (((np & 1) << 3) + b) * 8 + eo)) = *reinterpret_cast<const uint2*>(res);
            }
        }
    }

    // ---- f GEMM (K=512) swapped + fused fc epilogue
    {
        f32x4 facc[4][4];
#pragma unroll
        for (int q = 0; q < 4; ++q)
#pragma unroll
            for (int mt = 0; mt < 4; ++mt)
#pragma unroll
                for (int r = 0; r < 4; ++r) facc[q][mt][r] = 0.f;
#pragma unroll 4
        for (int kt = 0; kt < 16; ++kt) {
            bf16x8 av[4];
#pragma unroll
            for (int mt = 0; mt < 4; ++mt)
                av[mt] = *reinterpret_cast<const bf16x8*>(hX + cbase[mt] + kt * 512u);
#pragma unroll
            for (int q = 0; q < 4; ++q) {
                bf16x8 bf_ = fWfh[(size_t)((ntb + q) * 16 + kt) * 64 + lane];
#pragma unroll
                for (int mt = 0; mt < 4; ++mt)
                    facc[q][mt] = __builtin_amdgcn_mfma_f32_16x16x32_bf16(bf_, av[mt], facc[q][mt], 0, 0, 0);
            }
        }
#pragma unroll
        for (int q = 0; q < 4; ++q) {
            const int ct = ntb + q;
            float bf4[4];
            *reinterpret_cast<float4*>(bf4) = *reinterpret_cast<const float4*>(&bfh[ct * 16 + kr * 4]);
            const int colc = (ct >> 1) * 512 + (((ct & 1) << 1) + (kr >> 1)) * 128;
#pragma unroll
            for (int mh = 0; mh < 2; ++mh) {
                int pr = mh * 16 + cl;
                int p = pr >> 3, b = pr & 7;
                int np = nb + p;
                if (np >= n) continue;
                unsigned int cb0 = (unsigned int)(np * 8192 + colc + b * 8 + eo);
                ushort_t c0s[4], c1s[4];
                *reinterpret_cast<uint2*>(c0s) = *reinterpret_cast<const uint2*>(cX + cb0);
                *reinterpret_cast<uint2*>(c1s) = *reinterpret_cast<const uint2*>(cX + cb0 + 64);
                ushort_t res[4];
#pragma unroll
                for (int r = 0; r < 4; ++r) {
                    float xfv = xfa[q][mh][r];
                    float f0 = sigmoidf_(facc[q][mh][r] + bf4[r] + xfv);
                    float f1 = sigmoidf_(facc[q][mh + 2][r] + bf4[r] + xfv);
                    res[r] = f2b(f0 * b2f(c0s[r]) + f1 * b2f(c1s[r]));
                }
                *reinterpret_cast<uint2*>(cY + (unsigned int)((np >> 1) * 8192 + colc
                        + (((np & 1) << 3) + b) * 8 + eo)) = *reinterpret_cast<const uint2*>(res);
            }
        }
    }
}

// ---------------- iou (also leaf): 8 parents/block; SWAPPED-operand MFMA, no epi LDS,
// x staged in LDS (fragment layout); JSPAN col tiles per block, j = blockIdx.y*JSPAN+jj.
template <bool LEAF, int JSPAN>
__global__ __launch_bounds__(256) void iou_kernel(
    const ushort_t* __restrict__ xpk,
    const ushort_t* __restrict__ pWioux, const float* __restrict__ bioux,
    const ushort_t* __restrict__ pWiouh, const float* __restrict__ biouh,
    const ushort_t* __restrict__ hYsum, const ushort_t* __restrict__ cYfc,
    ushort_t* __restrict__ hOut, ushort_t* __restrict__ cOut,
    int start, int n)
{
    const int nb = blockIdx.x * 8;
    const int t = threadIdx.x;
    const int w = t >> 6, lane = t & 63;
    const int kr = lane >> 4, cl = lane & 15;

    __shared__ ushort_t xsl[4 * 5120];  // 40 KB (only LDS)

    {
        const ushort_t* xsrc = xpk + xlvl_base(start) + (size_t)(blockIdx.x * 4) * 5120;
        for (int i = t; i < 2560; i += 256)
            *reinterpret_cast<uint4*>(xsl + (size_t)i * 8) =
                *reinterpret_cast<const uint4*>(xsrc + (size_t)i * 8);
    }
    __syncthreads();

    const bf16x8* fWx = reinterpret_cast<const bf16x8*>(pWioux);
    const bf16x8* fWh = reinterpret_cast<const bf16x8*>(pWiouh);

    unsigned int hbase[4];
#pragma unroll
    for (int mt = 0; mt < 4; ++mt)
        hbase[mt] = (unsigned int)(((nb >> 1) + mt) * 8192 + lane * 8);

    const int eo = (kr & 1) * 4;

#pragma unroll 1
    for (int jj = 0; jj < JSPAN; ++jj) {
        const int j = blockIdx.y * JSPAN + jj;
        const int cnt = j * 4 + w;
        f32x4 acc[4][3];
#pragma unroll
        for (int mt = 0; mt < 4; ++mt)
#pragma unroll
            for (int q = 0; q < 3; ++q)
#pragma unroll
                for (int r = 0; r < 4; ++r) acc[mt][q][r] = 0.f;

#pragma unroll 2
        for (int kt = 0; kt < 10; ++kt) {
            bf16x8 av[4];
#pragma unroll
            for (int mt = 0; mt < 4; ++mt)
                av[mt] = *reinterpret_cast<const bf16x8*>(
                    xsl + mt * 5120 + kt * 512 + kr * 128 + cl * 8);
#pragma unroll
            for (int q = 0; q < 3; ++q) {
                bf16x8 bf_ = fWx[(size_t)((q * 32 + cnt) * 10 + kt) * 64 + lane];
#pragma unroll
                for (int mt = 0; mt < 4; ++mt)
                    acc[mt][q] = __builtin_amdgcn_mfma_f32_16x16x32_bf16(bf_, av[mt], acc[mt][q], 0, 0, 0);
            }
        }
        if (!LEAF) {
#pragma unroll 4
            for (int kt = 0; kt < 16; ++kt) {
                bf16x8 av[4];
#pragma unroll
                for (int mt = 0; mt < 4; ++mt)
                    av[mt] = *reinterpret_cast<const bf16x8*>(hYsum + hbase[mt] + kt * 512u);
#pragma unroll
                for (int q = 0; q < 3; ++q) {
                    bf16x8 bf_ = fWh[(size_t)((q * 32 + cnt) * 16 + kt) * 64 + lane];
#pragma unroll
                    for (int mt = 0; mt < 4; ++mt)
                        acc[mt][q] = __builtin_amdgcn_mfma_f32_16x16x32_bf16(bf_, av[mt], acc[mt][q], 0, 0, 0);
                }
            }
        }

        // fused epilogue: lane has i/o/u for 4 consecutive cols x 1 row
        const int nbase = cnt * 16 + kr * 4;
        float bi[4], bo[4], bu[4];
        {
            float x0[4], h0[4];
            *reinterpret_cast<float4*>(x0) = *reinterpret_cast<const float4*>(&bioux[nbase]);
            *reinterpret_cast<float4*>(h0) = *reinterpret_cast<const float4*>(&biouh[nbase]);
#pragma unroll
            for (int r = 0; r < 4; ++r) bi[r] = x0[r] + h0[r];
            *reinterpret_cast<float4*>(x0) = *reinterpret_cast<const float4*>(&bioux[nbase + 512]);
            *reinterpret_cast<float4*>(h0) = *reinterpret_cast<const float4*>(&biouh[nbase + 512]);
#pragma unroll
            for (int r = 0; r < 4; ++r) bo[r] = x0[r] + h0[r];
            *reinterpret_cast<float4*>(x0) = *reinterpret_cast<const float4*>(&bioux[nbase + 1024]);
            *reinterpret_cast<float4*>(h0) = *reinterpret_cast<const float4*>(&biouh[nbase + 1024]);
#pragma unroll
            for (int r = 0; r < 4; ++r) bu[r] = x0[r] + h0[r];
        }
        const int colc = (cnt >> 1) * 512 + (((cnt & 1) << 1) + (kr >> 1)) * 128;
#pragma unroll
        for (int mt = 0; mt < 4; ++mt) {
            int row = mt * 16 + cl;
            int p = row >> 3, b = row & 7;
            int np = nb + p;
            if (np >= n) continue;
            unsigned int off = (unsigned int)((np >> 1) * 8192 + colc
                                              + (((np & 1) << 3) + b) * 8 + eo);
            ushort_t fcs[4] = {0, 0, 0, 0};
            if (!LEAF) *reinterpret_cast<uint2*>(fcs) = *reinterpret_cast<const uint2*>(cYfc + off);
            ushort_t rc[4], rh[4];
#pragma unroll
            for (int r = 0; r < 4; ++r) {
                float iv = acc[mt][0][r] + bi[r];
                float ov = acc[mt][1][r] + bo[r];
                float uv = acc[mt][2][r] + bu[r];
                float cv = sigmoidf_(iv) * tanhf(uv) + b2f(fcs[r]);
                float hv = sigmoidf_(ov) * tanhf(cv);
                rc[r] = f2b(cv); rh[r] = f2b(hv);
            }
            *reinterpret_cast<uint2*>(cOut + off) = *reinterpret_cast<const uint2*>(rc);
            *reinterpret_cast<uint2*>(hOut + off) = *reinterpret_cast<const uint2*>(rh);
        }
    }
}

// ---------------- output: concat(c_root, h_root) per batch, FP32 (packed-layout read)
__global__ __launch_bounds__(256) void out_kernel(
    const ushort_t* __restrict__ hroot, const ushort_t* __restrict__ croot,
    float* __restrict__ out)
{
    int t = blockIdx.x * 256 + threadIdx.x;
    if (t >= B * 2 * HDIM) return;
    int b = t / (2 * HDIM);
    int j = t - b * 2 * HDIM;
    int col = (j < HDIM) ? j : j - HDIM;
    unsigned int o = pidx(b, col);
    out[t] = (j < HDIM) ? b2f(croot[o]) : b2f(hroot[o]);
}

__global__ void diag_kernel(float* out, float v) { out[0] = v; }

extern "C" void kernel_launch(void* const* d_in, const int* in_sizes, int n_in,
                              void* d_out, int out_size, void* d_ws, size_t ws_size,
                              hipStream_t stream)
{
    const float* inputs      = (const float*)d_in[0];
    const float* edge_inputs = (const float*)d_in[1];
    const float* Wioux       = (const float*)d_in[2];
    const float* bioux       = (const float*)d_in[3];
    const float* Wiouh       = (const float*)d_in[4];
    const float* biouh       = (const float*)d_in[5];
    const float* Wfx         = (const float*)d_in[6];
    const float* bfx         = (const float*)d_in[7];
    const float* Wfh         = (const float*)d_in[8];
    const float* bfh         = (const float*)d_in[9];
    const float* We          = (const float*)d_in[10];
    const float* be          = (const float*)d_in[11];
    float* out = (float*)d_out;

    const size_t szWioux = (size_t)96 * 10 * 64 * 8;
    const size_t szWfx   = (size_t)32 * 10 * 64 * 8;
    const size_t szWe    = (size_t)32 * 4  * 64 * 8;
    const size_t szWfh   = (size_t)32 * 16 * 64 * 8;
    const size_t szWiouh = (size_t)96 * 16 * 64 * 8;

    const size_t eXpk = (size_t)16384 * 2560;         // tile-granular levels
    const size_t eX   = (size_t)B * 8192 * HDIM;
    const size_t eY   = (size_t)B * 4096 * HDIM;

    const size_t need = (szWioux + szWfx + szWe + szWfh + szWiouh
                         + eXpk + 2 * eX + 2 * eY) * sizeof(ushort_t);  // ~288.7 MB
    if (ws_size < need) {
        diag_kernel<<<1, 1, 0, stream>>>(out, 2.0e8f);
        return;
    }

    ushort_t* p = (ushort_t*)d_ws;
    ushort_t* pWioux = p;            p += szWioux;
    ushort_t* pWfx   = p;            p += szWfx;
    ushort_t* pWe    = p;            p += szWe;
    ushort_t* pWfh   = p;            p += szWfh;
    ushort_t* pWiouh = p;            p += szWiouh;
    ushort_t* xpk = p;               p += eXpk;
    ushort_t* hX = p;                p += eX;
    ushort_t* cX = p;                p += eX;
    ushort_t* hY = p;                p += eY;
    ushort_t* cY = p;                p += eY;

    pack_kernel<<<(96 * 10 * 64 + 255) / 256, 256, 0, stream>>>(Wioux, pWioux, INDIM, 10, 96 * 10 * 64);
    pack_kernel<<<(32 * 10 * 64 + 255) / 256, 256, 0, stream>>>(Wfx,   pWfx,   INDIM, 10, 32 * 10 * 64);
    pack_kernel<<<(32 * 4  * 64 + 255) / 256, 256, 0, stream>>>(We,    pWe,    EDIM,  4,  32 * 4  * 64);
    pack_kernel<<<(32 * 16 * 64 + 255) / 256, 256, 0, stream>>>(Wfh,   pWfh,   HDIM,  16, 32 * 16 * 64);
    pack_kernel<<<(96 * 16 * 64 + 255) / 256, 256, 0, stream>>>(Wiouh, pWiouh, HDIM,  16, 96 * 16 * 64);
    xpack_kernel<<<(NN * 8 * 40 + 255) / 256, 256, 0, stream>>>(inputs, xpk);

    // leaf level: start=8191, n=8192
    iou_kernel<true, 8><<<dim3(1024, 1), 256, 0, stream>>>(
        xpk, pWioux, bioux, pWiouh, biouh, hY, cY, hX, cX, 8191, 8192);

    for (int lvl = 12; lvl >= 0; --lvl) {
        int start = (1 << lvl) - 1;
        int n = 1 << lvl;
        children_kernel<<<dim3((n + 3) / 4, 2), 256, 0, stream>>>(
            xpk, edge_inputs, pWfx, bfx, pWfh, bfh, pWe, be,
            hX, cX, hY, cY, start, n);
        if (n >= 2048) {
            iou_kernel<false, 8><<<dim3(n / 8, 1), 256, 0, stream>>>(
                xpk, pWioux, bioux, pWiouh, biouh, hY, cY, hX, cX, start, n);
        } else {
            iou_kernel<false, 1><<<dim3((n + 7) / 8, 8), 256, 0, stream>>>(
                xpk, pWioux, bioux, pWiouh, biouh, hY, cY, hX, cX, start, n);
        }
    }

    out_kernel<<<(B * 2 * HDIM + 255) / 256, 256, 0, stream>>>(hX, cX, out);
}